// Round 4
// baseline (647.932 us; speedup 1.0000x reference)
//
#include <hip/hip_runtime.h>

#define S_LEN  4096
#define DMODEL 2048
#define NHEADS 16
#define HDIM   128

typedef __bf16 bf16x8 __attribute__((ext_vector_type(8)));
typedef __bf16 bf16x2 __attribute__((ext_vector_type(2)));
typedef float  f32x4  __attribute__((ext_vector_type(4)));
typedef float  f32x16 __attribute__((ext_vector_type(16)));

__device__ __forceinline__ unsigned short f2b(float f) {
    unsigned int u = __float_as_uint(f);
    unsigned int r = (u + 0x7fffu + ((u >> 16) & 1u)) >> 16;
    return (unsigned short)r;
}

// pack two fp32 -> one dword of bf16 (lo = a, hi = b)
__device__ __forceinline__ unsigned int pkbf16(float a, float b) {
#if __has_builtin(__builtin_amdgcn_cvt_pk_bf16_f32)
    bf16x2 t = __builtin_amdgcn_cvt_pk_bf16_f32(a, b);
    return *(unsigned int*)&t;
#else
    return (unsigned int)f2b(a) | ((unsigned int)f2b(b) << 16);
#endif
}

__device__ __forceinline__ f32x4 mfma16(bf16x8 a, bf16x8 b, f32x4 c) {
    return __builtin_amdgcn_mfma_f32_16x16x32_bf16(a, b, c, 0, 0, 0);
}

__device__ __forceinline__ f32x16 mfma32(bf16x8 a, bf16x8 b, f32x16 c) {
    return __builtin_amdgcn_mfma_f32_32x32x16_bf16(a, b, c, 0, 0, 0);
}

// async global->LDS, 16B per lane; LDS dest = wave-uniform base + lane*16
__device__ __forceinline__ void ldg2lds16(const void* g, void* l) {
    __builtin_amdgcn_global_load_lds(
        (__attribute__((address_space(1))) void*)(void*)g,
        (__attribute__((address_space(3))) void*)l, 16, 0, 0);
}

// ---------------------------------------------------------------------------
// fp32 -> bf16 converts
// ---------------------------------------------------------------------------
__global__ __launch_bounds__(256) void cvt_bf16(
    const float* __restrict__ src, unsigned short* __restrict__ dst, int n4)
{
    int i = blockIdx.x * blockDim.x + threadIdx.x;
    if (i < n4) {
        float4 v = ((const float4*)src)[i];
        uint2 h;
        h.x = pkbf16(v.x, v.y); h.y = pkbf16(v.z, v.w);
        ((uint2*)dst)[i] = h;
    }
}

__global__ __launch_bounds__(256) void cvt_bf16_w4(
    const float* __restrict__ w0, const float* __restrict__ w1,
    const float* __restrict__ w2, const float* __restrict__ w3,
    unsigned short* __restrict__ d0, unsigned short* __restrict__ d1,
    unsigned short* __restrict__ d2, unsigned short* __restrict__ d3)
{
    const int z = blockIdx.y;
    const float* src = (z == 0) ? w0 : (z == 1) ? w1 : (z == 2) ? w2 : w3;
    unsigned short* dst = (z == 0) ? d0 : (z == 1) ? d1 : (z == 2) ? d2 : d3;
    int i = blockIdx.x * blockDim.x + threadIdx.x;
    float4 v = ((const float4*)src)[i];
    uint2 h;
    h.x = pkbf16(v.x, v.y); h.y = pkbf16(v.z, v.w);
    ((uint2*)dst)[i] = h;
}

// ---------------------------------------------------------------------------
// m97-structure bf16 GEMM (QKV variant)
// ---------------------------------------------------------------------------
__global__ __launch_bounds__(256, 2) void gemm_qkv(
    const unsigned short* __restrict__ xb,
    const unsigned short* __restrict__ Wqb, const float* __restrict__ bq,
    const unsigned short* __restrict__ Wkb, const float* __restrict__ bk,
    const unsigned short* __restrict__ Wvb, const float* __restrict__ bv,
    unsigned short* __restrict__ Qb, unsigned short* __restrict__ Kb,
    unsigned short* __restrict__ Vb)
{
    const int z = blockIdx.z;
    const unsigned short* B = (z == 0) ? Wqb : (z == 1) ? Wkb : Wvb;
    const float* bias        = (z == 0) ? bq  : (z == 1) ? bk  : bv;
    unsigned short* C        = (z == 0) ? Qb  : (z == 1) ? Kb  : Vb;
    const float oscale = (z == 0) ? 0.12751743f : 1.0f;  // log2(e)/sqrt(128)

    __shared__ alignas(16) unsigned short As[128 * 32];
    __shared__ alignas(16) unsigned short Bs[128 * 32];

    const int tid = threadIdx.x;
    const int m0 = blockIdx.y * 128, n0 = blockIdx.x * 128;
    const int w = tid >> 6, lane = tid & 63, lo = lane & 15, qd = lane >> 4;
    const int wm = (w >> 1) * 64, wn = (w & 1) * 64;
    const int rsel = lane >> 2, csel = (lane & 3) * 8;

    f32x4 acc[4][4] = {};

    for (int k0 = 0; k0 < DMODEL; k0 += 32) {
#pragma unroll
        for (int i = 0; i < 2; i++) {
            int c = w * 2 + i;
            ldg2lds16(&xb[(size_t)(m0 + c * 16 + rsel) * DMODEL + k0 + csel],
                      &As[c * 512]);
            ldg2lds16(&B [(size_t)(n0 + c * 16 + rsel) * DMODEL + k0 + csel],
                      &Bs[c * 512]);
        }
        __syncthreads();

        bf16x8 af[4], bfr[4];
#pragma unroll
        for (int i = 0; i < 4; i++)
            af[i] = *(const bf16x8*)&As[(wm + i * 16 + lo) * 32 + qd * 8];
#pragma unroll
        for (int j = 0; j < 4; j++)
            bfr[j] = *(const bf16x8*)&Bs[(wn + j * 16 + lo) * 32 + qd * 8];
#pragma unroll
        for (int i = 0; i < 4; i++)
#pragma unroll
            for (int j = 0; j < 4; j++)
                acc[i][j] = mfma16(af[i], bfr[j], acc[i][j]);
        __syncthreads();
    }

#pragma unroll
    for (int j = 0; j < 4; j++) {
        int n = n0 + wn + j * 16 + lo;
        float bv_ = bias[n];
#pragma unroll
        for (int i = 0; i < 4; i++) {
#pragma unroll
            for (int r = 0; r < 4; r++) {
                int m = m0 + wm + i * 16 + qd * 4 + r;
                C[(size_t)m * DMODEL + n] = f2b((acc[i][j][r] + bv_) * oscale);
            }
        }
    }
}

// Output projection variant: fp32 out + bias.
__global__ __launch_bounds__(256, 2) void gemm_out(
    const unsigned short* __restrict__ Aatt, const unsigned short* __restrict__ Wob,
    const float* __restrict__ bo, float* __restrict__ out)
{
    __shared__ alignas(16) unsigned short As[128 * 32];
    __shared__ alignas(16) unsigned short Bs[128 * 32];

    const int tid = threadIdx.x;
    const int m0 = blockIdx.y * 128, n0 = blockIdx.x * 128;
    const int w = tid >> 6, lane = tid & 63, lo = lane & 15, qd = lane >> 4;
    const int wm = (w >> 1) * 64, wn = (w & 1) * 64;
    const int rsel = lane >> 2, csel = (lane & 3) * 8;

    f32x4 acc[4][4] = {};

    for (int k0 = 0; k0 < DMODEL; k0 += 32) {
#pragma unroll
        for (int i = 0; i < 2; i++) {
            int c = w * 2 + i;
            ldg2lds16(&Aatt[(size_t)(m0 + c * 16 + rsel) * DMODEL + k0 + csel],
                      &As[c * 512]);
            ldg2lds16(&Wob [(size_t)(n0 + c * 16 + rsel) * DMODEL + k0 + csel],
                      &Bs[c * 512]);
        }
        __syncthreads();

        bf16x8 af[4], bfr[4];
#pragma unroll
        for (int i = 0; i < 4; i++)
            af[i] = *(const bf16x8*)&As[(wm + i * 16 + lo) * 32 + qd * 8];
#pragma unroll
        for (int j = 0; j < 4; j++)
            bfr[j] = *(const bf16x8*)&Bs[(wn + j * 16 + lo) * 32 + qd * 8];
#pragma unroll
        for (int i = 0; i < 4; i++)
#pragma unroll
            for (int j = 0; j < 4; j++)
                acc[i][j] = mfma16(af[i], bfr[j], acc[i][j]);
        __syncthreads();
    }

#pragma unroll
    for (int j = 0; j < 4; j++) {
        int n = n0 + wn + j * 16 + lo;
        float bv_ = bo[n];
#pragma unroll
        for (int i = 0; i < 4; i++) {
#pragma unroll
            for (int r = 0; r < 4; r++) {
                int m = m0 + wm + i * 16 + qd * 4 + r;
                out[(size_t)m * DMODEL + n] = acc[i][j][r] + bv_;
            }
        }
    }
}

// ---------------------------------------------------------------------------
// V transpose: Vb [s][n] -> Vt [n][s]
// ---------------------------------------------------------------------------
__global__ __launch_bounds__(256) void transpose_v(
    const unsigned short* __restrict__ Vb, unsigned short* __restrict__ Vt)
{
    __shared__ unsigned short tile[64 * 67];
    const int s0 = blockIdx.x * 64;
    const int d0 = blockIdx.y * 64;
    const int tid = threadIdx.x;
#pragma unroll
    for (int i = 0; i < 2; i++) {
        int chunk = tid + i * 256;
        int r = chunk >> 3, c8 = (chunk & 7) * 8;
        uint4 v = *(const uint4*)&Vb[(size_t)(s0 + r) * DMODEL + d0 + c8];
        const unsigned short* p = (const unsigned short*)&v;
#pragma unroll
        for (int j = 0; j < 8; j++) tile[r * 67 + c8 + j] = p[j];
    }
    __syncthreads();
#pragma unroll
    for (int i = 0; i < 2; i++) {
        int chunk = tid + i * 256;
        int r = chunk >> 3, c8 = (chunk & 7) * 8;
        unsigned short tmp[8];
#pragma unroll
        for (int j = 0; j < 8; j++) tmp[j] = tile[(c8 + j) * 67 + r];
        *(uint4*)&Vt[(size_t)(d0 + r) * S_LEN + s0 + c8] = *(uint4*)tmp;
    }
}

// ---------------------------------------------------------------------------
// Flash attention v9: v8 + occupancy fix + ping-pong phase staging.
//   v8 post-mortem: unified VGPR+AGPR ~164 (>128) halved occupancy to
//   2 waves/SIMD (m69 halving law; measured 23%); staging had ZERO latency
//   overlap (stage -> immediate barrier drain). No pipe >40% => latency-bound.
//   v9:
//   (1) __launch_bounds__(256,4) + register-lean softmax (fused exp2->pack,
//       no p[16] array) to fit unified regs <=128 -> 4 waves/SIMD,
//       4 blocks/CU.
//   (2) Ping-pong staging, zero extra LDS: K and V are consumed in
//       different phases, so stage V(t) at the top of the QK^T phase
//       (drained by mid-barrier) and K(t+1) at the top of the PV phase
//       (drained by end-barrier). Each stage hides under a full MFMA+VALU
//       phase. Race-free: Ks reads end at mid-sync before K(t+1) writes;
//       Vts reads end at end-sync before V(t+1) writes.
// ---------------------------------------------------------------------------
__global__ __launch_bounds__(256, 4) void attn_kernel(
    const unsigned short* __restrict__ Qb, const unsigned short* __restrict__ Kb,
    const unsigned short* __restrict__ Vt, unsigned short* __restrict__ Ob)
{
    const int id = blockIdx.x;
    const int xcd = id & 7, slot = id >> 3;          // slot 0..127
    const int h  = (xcd << 1) | (slot >> 6);         // 2 heads per XCD, one at a time
    const int q0 = (slot & 63) * 64;                 // 64-query block

    __shared__ alignas(16) unsigned char smem[33280];
    unsigned short* Ks  = (unsigned short*)smem;            // [64][128] 16KB, chunk-swizzled
    unsigned short* Vts = (unsigned short*)(smem + 16384);  // [128][64] 16KB, chunk-swizzled
    float* Of = (float*)smem;                               // [2][32][128] 32KB (epilogue alias)
    float* Lf = (float*)(smem + 32768);                     // [2 qw][2 kw][32 q]

    const int tid = threadIdx.x;
    const int w = tid >> 6, lane = tid & 63;
    const int qw = w >> 1, kw = w & 1;               // q-half / key-half of wave
    const int l31 = lane & 31, hi = lane >> 5;
    const int sw7 = l31 & 7;                          // row&7 for all swizzled reads

    // Q fragments direct from global: lane's q row = q0 + qw*32 + l31.
    // B-frag (k x n): col n = l31 = q, k = sl*16 + hi*8 + j.
    bf16x8 qf[8];
    {
        const unsigned short* qrow =
            &Qb[(size_t)(q0 + qw * 32 + l31) * DMODEL + h * HDIM];
#pragma unroll
        for (int sl = 0; sl < 8; sl++)
            qf[sl] = *(const bf16x8*)&qrow[sl * 16 + hi * 8];
    }

    f32x16 o_acc[4] = {};     // dt: d cols dt*32 + l31; rows = 16 q per C layout
    float l_run = 0.f;

    const int krow = kw * 32 + l31;                   // A-row (key) for QK^T

    // K staging: wave w -> key rows w*16..w*16+15 (chunk c at pos c^(r&7))
#define STAGE_K(key0_)                                                        \
    {                                                                         \
        _Pragma("unroll")                                                     \
        for (int i = 0; i < 4; i++) {                                         \
            int r = w * 16 + i * 4 + (lane >> 4);                             \
            int c = (lane & 15) ^ (r & 7);                                    \
            ldg2lds16(&Kb[(size_t)((key0_) + r) * DMODEL + h * HDIM + c * 8], \
                      &Ks[(w * 16 + i * 4) * 128]);                           \
        }                                                                     \
    }
    // V staging: wave w -> d rows w*32..w*32+31
#define STAGE_V(key0_)                                                        \
    {                                                                         \
        _Pragma("unroll")                                                     \
        for (int i = 0; i < 4; i++) {                                         \
            int r = w * 32 + i * 8 + (lane >> 3);                             \
            int c = (lane & 7) ^ (r & 7);                                     \
            ldg2lds16(&Vt[(size_t)(h * HDIM + r) * S_LEN + (key0_) + c * 8],  \
                      &Vts[(w * 32 + i * 8) * 64]);                           \
        }                                                                     \
    }

    // prologue: K(0) only; V(0) is staged under QK^T(0).
    STAGE_K(0);
    __syncthreads();

    for (int kb = 0; kb < S_LEN / 64; kb++) {
        const int key0 = kb * 64;

        // ---- Phase A: issue V(t) stage; QK^T(t); softmax+pack ----
        STAGE_V(key0);

        // S^T[32 key][32 q] = K Q^T : A = K rows (m=key), B = Q (n=q).
        f32x16 s = {};
        __builtin_amdgcn_s_setprio(1);
#pragma unroll
        for (int sl = 0; sl < 8; sl++) {
            bf16x8 kf = *(const bf16x8*)
                &Ks[krow * 128 + (((2 * sl + hi) ^ sw7) * 8)];
            s = mfma32(kf, qf[sl], s);
        }
        __builtin_amdgcn_s_setprio(0);

        // In-register softmax, fused exp2 -> pack (register-lean: no p[16]).
        // Lane holds q = l31, keys key(reg,hi) = (reg&3)+8*(reg>>2)+4*hi.
        // T12: A-frag dword d of k-slice k2 needs cvtpk(p[2(d&1)+8*k2+4*hi_rd])
        // from lane-group (d>>1) => swap(C0,C2)->(dw0,dw2), swap(C1,C3)->(dw1,dw3).
        bf16x8 pa0, pa1;
        {
            float ls = 0.f;
#pragma unroll
            for (int k2 = 0; k2 < 2; k2++) {
                float e0 = __builtin_amdgcn_exp2f(s[8 * k2 + 0]);
                float e1 = __builtin_amdgcn_exp2f(s[8 * k2 + 1]);
                float e2 = __builtin_amdgcn_exp2f(s[8 * k2 + 2]);
                float e3 = __builtin_amdgcn_exp2f(s[8 * k2 + 3]);
                float e4 = __builtin_amdgcn_exp2f(s[8 * k2 + 4]);
                float e5 = __builtin_amdgcn_exp2f(s[8 * k2 + 5]);
                float e6 = __builtin_amdgcn_exp2f(s[8 * k2 + 6]);
                float e7 = __builtin_amdgcn_exp2f(s[8 * k2 + 7]);
                ls += ((e0 + e1) + (e2 + e3)) + ((e4 + e5) + (e6 + e7));
                unsigned int c0 = pkbf16(e0, e1);
                unsigned int c1 = pkbf16(e2, e3);
                unsigned int c2 = pkbf16(e4, e5);
                unsigned int c3 = pkbf16(e6, e7);
                asm("v_permlane32_swap_b32 %0, %1" : "+v"(c0), "+v"(c2));
                asm("v_permlane32_swap_b32 %0, %1" : "+v"(c1), "+v"(c3));
                uint4 u; u.x = c0; u.y = c1; u.z = c2; u.w = c3;
                if (k2 == 0) pa0 = *(bf16x8*)&u; else pa1 = *(bf16x8*)&u;
            }
            l_run += ls;
        }

        // mid barrier: drains V(t); all waves done reading Ks.
        __syncthreads();

        // ---- Phase B: issue K(t+1) stage; PV(t) ----
        if (kb + 1 < S_LEN / 64) STAGE_K((kb + 1) * 64);

        __builtin_amdgcn_s_setprio(1);
#pragma unroll
        for (int k2 = 0; k2 < 2; k2++) {
            const int gch = 4 * kw + 2 * k2 + hi;   // 16B chunk in 64-key row
            bf16x8 pf = (k2 == 0) ? pa0 : pa1;
#pragma unroll
            for (int dt = 0; dt < 4; dt++) {
                bf16x8 vf = *(const bf16x8*)
                    &Vts[(dt * 32 + l31) * 64 + ((gch ^ sw7) * 8)];
                o_acc[dt] = mfma32(pf, vf, o_acc[dt]);
            }
        }
        __builtin_amdgcn_s_setprio(0);

        // end barrier: drains K(t+1); all waves done reading Vts.
        __syncthreads();
    }
#undef STAGE_K
#undef STAGE_V

    // ---- epilogue: merge kw halves (O and l additive; no-max softmax) ----
    float l = l_run + __shfl_xor(l_run, 32);   // full 32-key half per lane's q

    if (kw == 1) {
#pragma unroll
        for (int dt = 0; dt < 4; dt++)
#pragma unroll
            for (int r = 0; r < 16; r++) {
                int row = (r & 3) + 8 * (r >> 2) + 4 * hi;
                Of[(qw * 32 + row) * 128 + dt * 32 + l31] = o_acc[dt][r];
            }
    }
    if (hi == 0) Lf[(qw * 2 + kw) * 32 + l31] = l;
    __syncthreads();

    if (kw == 0) {
        float linv[16];
#pragma unroll
        for (int r = 0; r < 16; r++) {
            int row = (r & 3) + 8 * (r >> 2) + 4 * hi;
            linv[r] = 1.0f / (Lf[(qw * 2 + 0) * 32 + row] +
                              Lf[(qw * 2 + 1) * 32 + row]);
        }
#pragma unroll
        for (int dt = 0; dt < 4; dt++)
#pragma unroll
            for (int r = 0; r < 16; r++) {
                int row = (r & 3) + 8 * (r >> 2) + 4 * hi;
                float v = o_acc[dt][r] + Of[(qw * 32 + row) * 128 + dt * 32 + l31];
                Ob[(size_t)(q0 + qw * 32 + row) * DMODEL + h * HDIM + dt * 32 + l31]
                    = f2b(v * linv[r]);
            }
    }
}

// ---------------------------------------------------------------------------
extern "C" void kernel_launch(void* const* d_in, const int* in_sizes, int n_in,
                              void* d_out, int out_size, void* d_ws, size_t ws_size,
                              hipStream_t stream)
{
    const float* x  = (const float*)d_in[0];
    const float* Wq = (const float*)d_in[1];
    const float* bq = (const float*)d_in[2];
    const float* Wk = (const float*)d_in[3];
    const float* bk = (const float*)d_in[4];
    const float* Wv = (const float*)d_in[5];
    const float* bv = (const float*)d_in[6];
    const float* Wo = (const float*)d_in[7];
    const float* bo = (const float*)d_in[8];
    float* out = (float*)d_out;

    const size_t N = (size_t)S_LEN * DMODEL;   // 8M elems
    const size_t W = (size_t)DMODEL * DMODEL;  // 4M elems
    unsigned short* Qb  = (unsigned short*)d_ws;
    unsigned short* Kb  = Qb + N;
    unsigned short* Vb  = Kb + N;
    unsigned short* xbv = Vb + N;
    unsigned short* Wqb = xbv + N;
    unsigned short* Wkb = Wqb + W;
    unsigned short* Wvb = Wkb + W;
    unsigned short* Wob = Wvb + W;
    unsigned short* Vt  = xbv;   // alias after gemm_qkv
    unsigned short* Ob  = Vb;    // alias after transpose

    cvt_bf16<<<(int)(N / 4 / 256), 256, 0, stream>>>(x, xbv, (int)(N / 4));
    cvt_bf16_w4<<<dim3((unsigned)(W / 4 / 256), 4), 256, 0, stream>>>(
        Wq, Wk, Wv, Wo, Wqb, Wkb, Wvb, Wob);

    gemm_qkv<<<dim3(DMODEL / 128, S_LEN / 128, 3), 256, 0, stream>>>(
        xbv, Wqb, bq, Wkb, bk, Wvb, bv, Qb, Kb, Vb);

    transpose_v<<<dim3(S_LEN / 64, DMODEL / 64), 256, 0, stream>>>(Vb, Vt);

    attn_kernel<<<1024, 256, 0, stream>>>(Qb, Kb, Vt, Ob);

    gemm_out<<<dim3(DMODEL / 128, S_LEN / 128), 256, 0, stream>>>(Ob, Wob, bo, out);
}

// Round 5
// 492.975 us; speedup vs baseline: 1.3143x; 1.3143x over previous
//
#include <hip/hip_runtime.h>

#define S_LEN  4096
#define DMODEL 2048
#define NHEADS 16
#define HDIM   128

typedef __bf16 bf16x8 __attribute__((ext_vector_type(8)));
typedef __bf16 bf16x2 __attribute__((ext_vector_type(2)));
typedef float  f32x4  __attribute__((ext_vector_type(4)));
typedef float  f32x16 __attribute__((ext_vector_type(16)));

__device__ __forceinline__ unsigned short f2b(float f) {
    unsigned int u = __float_as_uint(f);
    unsigned int r = (u + 0x7fffu + ((u >> 16) & 1u)) >> 16;
    return (unsigned short)r;
}

// pack two fp32 -> one dword of bf16 (lo = a, hi = b)
__device__ __forceinline__ unsigned int pkbf16(float a, float b) {
#if __has_builtin(__builtin_amdgcn_cvt_pk_bf16_f32)
    bf16x2 t = __builtin_amdgcn_cvt_pk_bf16_f32(a, b);
    return *(unsigned int*)&t;
#else
    return (unsigned int)f2b(a) | ((unsigned int)f2b(b) << 16);
#endif
}

__device__ __forceinline__ f32x4 mfma16(bf16x8 a, bf16x8 b, f32x4 c) {
    return __builtin_amdgcn_mfma_f32_16x16x32_bf16(a, b, c, 0, 0, 0);
}

__device__ __forceinline__ f32x16 mfma32(bf16x8 a, bf16x8 b, f32x16 c) {
    return __builtin_amdgcn_mfma_f32_32x32x16_bf16(a, b, c, 0, 0, 0);
}

// async global->LDS, 16B per lane; LDS dest = wave-uniform base + lane*16
__device__ __forceinline__ void ldg2lds16(const void* g, void* l) {
    __builtin_amdgcn_global_load_lds(
        (__attribute__((address_space(1))) void*)(void*)g,
        (__attribute__((address_space(3))) void*)l, 16, 0, 0);
}

// ---------------------------------------------------------------------------
// fp32 -> bf16 converts
// ---------------------------------------------------------------------------
__global__ __launch_bounds__(256) void cvt_bf16(
    const float* __restrict__ src, unsigned short* __restrict__ dst, int n4)
{
    int i = blockIdx.x * blockDim.x + threadIdx.x;
    if (i < n4) {
        float4 v = ((const float4*)src)[i];
        uint2 h;
        h.x = pkbf16(v.x, v.y); h.y = pkbf16(v.z, v.w);
        ((uint2*)dst)[i] = h;
    }
}

__global__ __launch_bounds__(256) void cvt_bf16_w4(
    const float* __restrict__ w0, const float* __restrict__ w1,
    const float* __restrict__ w2, const float* __restrict__ w3,
    unsigned short* __restrict__ d0, unsigned short* __restrict__ d1,
    unsigned short* __restrict__ d2, unsigned short* __restrict__ d3)
{
    const int z = blockIdx.y;
    const float* src = (z == 0) ? w0 : (z == 1) ? w1 : (z == 2) ? w2 : w3;
    unsigned short* dst = (z == 0) ? d0 : (z == 1) ? d1 : (z == 2) ? d2 : d3;
    int i = blockIdx.x * blockDim.x + threadIdx.x;
    float4 v = ((const float4*)src)[i];
    uint2 h;
    h.x = pkbf16(v.x, v.y); h.y = pkbf16(v.z, v.w);
    ((uint2*)dst)[i] = h;
}

// ---------------------------------------------------------------------------
// m97-structure bf16 GEMM (QKV variant)
// ---------------------------------------------------------------------------
__global__ __launch_bounds__(256, 2) void gemm_qkv(
    const unsigned short* __restrict__ xb,
    const unsigned short* __restrict__ Wqb, const float* __restrict__ bq,
    const unsigned short* __restrict__ Wkb, const float* __restrict__ bk,
    const unsigned short* __restrict__ Wvb, const float* __restrict__ bv,
    unsigned short* __restrict__ Qb, unsigned short* __restrict__ Kb,
    unsigned short* __restrict__ Vb)
{
    const int z = blockIdx.z;
    const unsigned short* B = (z == 0) ? Wqb : (z == 1) ? Wkb : Wvb;
    const float* bias        = (z == 0) ? bq  : (z == 1) ? bk  : bv;
    unsigned short* C        = (z == 0) ? Qb  : (z == 1) ? Kb  : Vb;
    const float oscale = (z == 0) ? 0.12751743f : 1.0f;  // log2(e)/sqrt(128)

    __shared__ alignas(16) unsigned short As[128 * 32];
    __shared__ alignas(16) unsigned short Bs[128 * 32];

    const int tid = threadIdx.x;
    const int m0 = blockIdx.y * 128, n0 = blockIdx.x * 128;
    const int w = tid >> 6, lane = tid & 63, lo = lane & 15, qd = lane >> 4;
    const int wm = (w >> 1) * 64, wn = (w & 1) * 64;
    const int rsel = lane >> 2, csel = (lane & 3) * 8;

    f32x4 acc[4][4] = {};

    for (int k0 = 0; k0 < DMODEL; k0 += 32) {
#pragma unroll
        for (int i = 0; i < 2; i++) {
            int c = w * 2 + i;
            ldg2lds16(&xb[(size_t)(m0 + c * 16 + rsel) * DMODEL + k0 + csel],
                      &As[c * 512]);
            ldg2lds16(&B [(size_t)(n0 + c * 16 + rsel) * DMODEL + k0 + csel],
                      &Bs[c * 512]);
        }
        __syncthreads();

        bf16x8 af[4], bfr[4];
#pragma unroll
        for (int i = 0; i < 4; i++)
            af[i] = *(const bf16x8*)&As[(wm + i * 16 + lo) * 32 + qd * 8];
#pragma unroll
        for (int j = 0; j < 4; j++)
            bfr[j] = *(const bf16x8*)&Bs[(wn + j * 16 + lo) * 32 + qd * 8];
#pragma unroll
        for (int i = 0; i < 4; i++)
#pragma unroll
            for (int j = 0; j < 4; j++)
                acc[i][j] = mfma16(af[i], bfr[j], acc[i][j]);
        __syncthreads();
    }

#pragma unroll
    for (int j = 0; j < 4; j++) {
        int n = n0 + wn + j * 16 + lo;
        float bv_ = bias[n];
#pragma unroll
        for (int i = 0; i < 4; i++) {
#pragma unroll
            for (int r = 0; r < 4; r++) {
                int m = m0 + wm + i * 16 + qd * 4 + r;
                C[(size_t)m * DMODEL + n] = f2b((acc[i][j][r] + bv_) * oscale);
            }
        }
    }
}

// Output projection variant: fp32 out + bias.
__global__ __launch_bounds__(256, 2) void gemm_out(
    const unsigned short* __restrict__ Aatt, const unsigned short* __restrict__ Wob,
    const float* __restrict__ bo, float* __restrict__ out)
{
    __shared__ alignas(16) unsigned short As[128 * 32];
    __shared__ alignas(16) unsigned short Bs[128 * 32];

    const int tid = threadIdx.x;
    const int m0 = blockIdx.y * 128, n0 = blockIdx.x * 128;
    const int w = tid >> 6, lane = tid & 63, lo = lane & 15, qd = lane >> 4;
    const int wm = (w >> 1) * 64, wn = (w & 1) * 64;
    const int rsel = lane >> 2, csel = (lane & 3) * 8;

    f32x4 acc[4][4] = {};

    for (int k0 = 0; k0 < DMODEL; k0 += 32) {
#pragma unroll
        for (int i = 0; i < 2; i++) {
            int c = w * 2 + i;
            ldg2lds16(&Aatt[(size_t)(m0 + c * 16 + rsel) * DMODEL + k0 + csel],
                      &As[c * 512]);
            ldg2lds16(&Wob [(size_t)(n0 + c * 16 + rsel) * DMODEL + k0 + csel],
                      &Bs[c * 512]);
        }
        __syncthreads();

        bf16x8 af[4], bfr[4];
#pragma unroll
        for (int i = 0; i < 4; i++)
            af[i] = *(const bf16x8*)&As[(wm + i * 16 + lo) * 32 + qd * 8];
#pragma unroll
        for (int j = 0; j < 4; j++)
            bfr[j] = *(const bf16x8*)&Bs[(wn + j * 16 + lo) * 32 + qd * 8];
#pragma unroll
        for (int i = 0; i < 4; i++)
#pragma unroll
            for (int j = 0; j < 4; j++)
                acc[i][j] = mfma16(af[i], bfr[j], acc[i][j]);
        __syncthreads();
    }

#pragma unroll
    for (int j = 0; j < 4; j++) {
        int n = n0 + wn + j * 16 + lo;
        float bv_ = bo[n];
#pragma unroll
        for (int i = 0; i < 4; i++) {
#pragma unroll
            for (int r = 0; r < 4; r++) {
                int m = m0 + wm + i * 16 + qd * 4 + r;
                out[(size_t)m * DMODEL + n] = acc[i][j][r] + bv_;
            }
        }
    }
}

// ---------------------------------------------------------------------------
// V transpose: Vb [s][n] -> Vt [n][s]
// ---------------------------------------------------------------------------
__global__ __launch_bounds__(256) void transpose_v(
    const unsigned short* __restrict__ Vb, unsigned short* __restrict__ Vt)
{
    __shared__ unsigned short tile[64 * 67];
    const int s0 = blockIdx.x * 64;
    const int d0 = blockIdx.y * 64;
    const int tid = threadIdx.x;
#pragma unroll
    for (int i = 0; i < 2; i++) {
        int chunk = tid + i * 256;
        int r = chunk >> 3, c8 = (chunk & 7) * 8;
        uint4 v = *(const uint4*)&Vb[(size_t)(s0 + r) * DMODEL + d0 + c8];
        const unsigned short* p = (const unsigned short*)&v;
#pragma unroll
        for (int j = 0; j < 8; j++) tile[r * 67 + c8 + j] = p[j];
    }
    __syncthreads();
#pragma unroll
    for (int i = 0; i < 2; i++) {
        int chunk = tid + i * 256;
        int r = chunk >> 3, c8 = (chunk & 7) * 8;
        unsigned short tmp[8];
#pragma unroll
        for (int j = 0; j < 8; j++) tmp[j] = tile[(c8 + j) * 67 + r];
        *(uint4*)&Vt[(size_t)(d0 + r) * S_LEN + s0 + c8] = *(uint4*)tmp;
    }
}

// ---------------------------------------------------------------------------
// Flash attention v10: 32x32 in-reg-P + FULL K/V double-buffer, 1 barrier/tile.
//   v9 post-mortem: __launch_bounds__(256,4) forced unified regs <=128; the
//   design needs ~164 -> scratch spill (WRITE_SIZE 16->69 MB, FETCH 28->670 MB,
//   memory-bound at 2.1 TB/s). Also learned (v8): ~164 regs lands at
//   2 waves/SIMD (no 3-wave step) -> design must win per-wave, not on TLP.
//   v10: accept 2 blocks/CU and spend the LDS headroom: double-buffer BOTH
//   K and V (64 KB) -> ONE barrier per tile. Stage(t+1) issued at top of
//   iter t (hides under the full iteration's MFMA+VALU); QK^T + softmax +
//   PV run straight through with no internal barrier (current buffers were
//   complete before the iter; only hazard is buffer reuse, covered by the
//   end barrier). launch_bounds(256,2) -> no spill possible.
// ---------------------------------------------------------------------------
__global__ __launch_bounds__(256, 2) void attn_kernel(
    const unsigned short* __restrict__ Qb, const unsigned short* __restrict__ Kb,
    const unsigned short* __restrict__ Vt, unsigned short* __restrict__ Ob)
{
    const int id = blockIdx.x;
    const int xcd = id & 7, slot = id >> 3;          // slot 0..127
    const int h  = (xcd << 1) | (slot >> 6);         // 2 heads per XCD
    const int q0 = (slot & 63) * 64;                 // 64-query block

    __shared__ alignas(16) unsigned char smem[66048];
    unsigned short* Ks0  = (unsigned short*)smem;            // [64][128] 16KB swz
    unsigned short* Vts0 = (unsigned short*)(smem + 16384);  // [128][64] 16KB swz
    unsigned short* Ks1  = (unsigned short*)(smem + 32768);
    unsigned short* Vts1 = (unsigned short*)(smem + 49152);
    float* Of = (float*)smem;                                // [2][32][128] 32KB epilogue alias
    float* Lf = (float*)(smem + 65536);                      // [2 qw][2 kw][32 q]

    const int tid = threadIdx.x;
    const int w = tid >> 6, lane = tid & 63;
    const int qw = w >> 1, kw = w & 1;               // q-half / key-half of wave
    const int l31 = lane & 31, hi = lane >> 5;
    const int sw7 = l31 & 7;                          // row&7 for swizzled reads

    // Q fragments direct from global: lane's q row = q0 + qw*32 + l31.
    // B-frag (k x n): col n = l31 = q, k = sl*16 + hi*8 + j.
    bf16x8 qf[8];
    {
        const unsigned short* qrow =
            &Qb[(size_t)(q0 + qw * 32 + l31) * DMODEL + h * HDIM];
#pragma unroll
        for (int sl = 0; sl < 8; sl++)
            qf[sl] = *(const bf16x8*)&qrow[sl * 16 + hi * 8];
    }

    f32x16 o_acc[4] = {};     // dt: d cols dt*32 + l31
    float l_run = 0.f;

    const int krow = kw * 32 + l31;                   // A-row (key) for QK^T

    // K staging: wave w -> key rows w*16..w*16+15 (chunk c at pos c^(r&7))
#define STAGE_K(dst_, key0_)                                                  \
    {                                                                         \
        _Pragma("unroll")                                                     \
        for (int i = 0; i < 4; i++) {                                         \
            int r = w * 16 + i * 4 + (lane >> 4);                             \
            int c = (lane & 15) ^ (r & 7);                                    \
            ldg2lds16(&Kb[(size_t)((key0_) + r) * DMODEL + h * HDIM + c * 8], \
                      &(dst_)[(w * 16 + i * 4) * 128]);                       \
        }                                                                     \
    }
    // V staging: wave w -> d rows w*32..w*32+31
#define STAGE_V(dst_, key0_)                                                  \
    {                                                                         \
        _Pragma("unroll")                                                     \
        for (int i = 0; i < 4; i++) {                                         \
            int r = w * 32 + i * 8 + (lane >> 3);                             \
            int c = (lane & 7) ^ (r & 7);                                     \
            ldg2lds16(&Vt[(size_t)(h * HDIM + r) * S_LEN + (key0_) + c * 8],  \
                      &(dst_)[(w * 32 + i * 8) * 64]);                        \
        }                                                                     \
    }

    // One full tile iteration: prefetch tile (kbn) into (KsN,VtsN), compute
    // QK^T+softmax+PV on (KsC,VtsC), single end barrier (drains prefetch +
    // protects buffer reuse).
#define ATTN_ITER(KsC, VtsC, KsN, VtsN, kbn)                                  \
    {                                                                         \
        if ((kbn) < S_LEN / 64) {                                             \
            STAGE_K(KsN, (kbn) * 64);                                         \
            STAGE_V(VtsN, (kbn) * 64);                                        \
        }                                                                     \
        f32x16 s = {};                                                        \
        __builtin_amdgcn_s_setprio(1);                                        \
        _Pragma("unroll")                                                     \
        for (int sl = 0; sl < 8; sl++) {                                      \
            bf16x8 kf = *(const bf16x8*)                                      \
                &(KsC)[krow * 128 + (((2 * sl + hi) ^ sw7) * 8)];             \
            s = mfma32(kf, qf[sl], s);                                        \
        }                                                                     \
        __builtin_amdgcn_s_setprio(0);                                        \
        bf16x8 pa0, pa1;                                                      \
        {                                                                     \
            float ls = 0.f;                                                   \
            _Pragma("unroll")                                                 \
            for (int k2 = 0; k2 < 2; k2++) {                                  \
                float e0 = __builtin_amdgcn_exp2f(s[8 * k2 + 0]);             \
                float e1 = __builtin_amdgcn_exp2f(s[8 * k2 + 1]);             \
                float e2 = __builtin_amdgcn_exp2f(s[8 * k2 + 2]);             \
                float e3 = __builtin_amdgcn_exp2f(s[8 * k2 + 3]);             \
                float e4 = __builtin_amdgcn_exp2f(s[8 * k2 + 4]);             \
                float e5 = __builtin_amdgcn_exp2f(s[8 * k2 + 5]);             \
                float e6 = __builtin_amdgcn_exp2f(s[8 * k2 + 6]);             \
                float e7 = __builtin_amdgcn_exp2f(s[8 * k2 + 7]);             \
                ls += ((e0 + e1) + (e2 + e3)) + ((e4 + e5) + (e6 + e7));      \
                unsigned int c0 = pkbf16(e0, e1);                             \
                unsigned int c1 = pkbf16(e2, e3);                             \
                unsigned int c2 = pkbf16(e4, e5);                             \
                unsigned int c3 = pkbf16(e6, e7);                             \
                asm("v_permlane32_swap_b32 %0, %1" : "+v"(c0), "+v"(c2));     \
                asm("v_permlane32_swap_b32 %0, %1" : "+v"(c1), "+v"(c3));     \
                uint4 u; u.x = c0; u.y = c1; u.z = c2; u.w = c3;              \
                if (k2 == 0) pa0 = *(bf16x8*)&u; else pa1 = *(bf16x8*)&u;     \
            }                                                                 \
            l_run += ls;                                                      \
        }                                                                     \
        __builtin_amdgcn_s_setprio(1);                                        \
        _Pragma("unroll")                                                     \
        for (int k2 = 0; k2 < 2; k2++) {                                      \
            const int gch = 4 * kw + 2 * k2 + hi;                             \
            bf16x8 pf = (k2 == 0) ? pa0 : pa1;                                \
            _Pragma("unroll")                                                 \
            for (int dt = 0; dt < 4; dt++) {                                  \
                bf16x8 vf = *(const bf16x8*)                                  \
                    &(VtsC)[(dt * 32 + l31) * 64 + ((gch ^ sw7) * 8)];        \
                o_acc[dt] = mfma32(pf, vf, o_acc[dt]);                        \
            }                                                                 \
        }                                                                     \
        __builtin_amdgcn_s_setprio(0);                                        \
        __syncthreads();                                                      \
    }

    // prologue: stage tile 0 into buf0
    STAGE_K(Ks0, 0);
    STAGE_V(Vts0, 0);
    __syncthreads();

    for (int kb = 0; kb < S_LEN / 64; kb += 2) {
        ATTN_ITER(Ks0, Vts0, Ks1, Vts1, kb + 1);
        ATTN_ITER(Ks1, Vts1, Ks0, Vts0, kb + 2);
    }
#undef ATTN_ITER
#undef STAGE_K
#undef STAGE_V

    // ---- epilogue: merge kw halves (O and l additive; no-max softmax) ----
    float l = l_run + __shfl_xor(l_run, 32);   // full 32-key half per lane's q

    if (kw == 1) {
#pragma unroll
        for (int dt = 0; dt < 4; dt++)
#pragma unroll
            for (int r = 0; r < 16; r++) {
                int row = (r & 3) + 8 * (r >> 2) + 4 * hi;
                Of[(qw * 32 + row) * 128 + dt * 32 + l31] = o_acc[dt][r];
            }
    }
    if (hi == 0) Lf[(qw * 2 + kw) * 32 + l31] = l;
    __syncthreads();

    if (kw == 0) {
        float linv[16];
#pragma unroll
        for (int r = 0; r < 16; r++) {
            int row = (r & 3) + 8 * (r >> 2) + 4 * hi;
            linv[r] = 1.0f / (Lf[(qw * 2 + 0) * 32 + row] +
                              Lf[(qw * 2 + 1) * 32 + row]);
        }
#pragma unroll
        for (int dt = 0; dt < 4; dt++)
#pragma unroll
            for (int r = 0; r < 16; r++) {
                int row = (r & 3) + 8 * (r >> 2) + 4 * hi;
                float v = o_acc[dt][r] + Of[(qw * 32 + row) * 128 + dt * 32 + l31];
                Ob[(size_t)(q0 + qw * 32 + row) * DMODEL + h * HDIM + dt * 32 + l31]
                    = f2b(v * linv[r]);
            }
    }
}

// ---------------------------------------------------------------------------
extern "C" void kernel_launch(void* const* d_in, const int* in_sizes, int n_in,
                              void* d_out, int out_size, void* d_ws, size_t ws_size,
                              hipStream_t stream)
{
    const float* x  = (const float*)d_in[0];
    const float* Wq = (const float*)d_in[1];
    const float* bq = (const float*)d_in[2];
    const float* Wk = (const float*)d_in[3];
    const float* bk = (const float*)d_in[4];
    const float* Wv = (const float*)d_in[5];
    const float* bv = (const float*)d_in[6];
    const float* Wo = (const float*)d_in[7];
    const float* bo = (const float*)d_in[8];
    float* out = (float*)d_out;

    const size_t N = (size_t)S_LEN * DMODEL;   // 8M elems
    const size_t W = (size_t)DMODEL * DMODEL;  // 4M elems
    unsigned short* Qb  = (unsigned short*)d_ws;
    unsigned short* Kb  = Qb + N;
    unsigned short* Vb  = Kb + N;
    unsigned short* xbv = Vb + N;
    unsigned short* Wqb = xbv + N;
    unsigned short* Wkb = Wqb + W;
    unsigned short* Wvb = Wkb + W;
    unsigned short* Wob = Wvb + W;
    unsigned short* Vt  = xbv;   // alias after gemm_qkv
    unsigned short* Ob  = Vb;    // alias after transpose

    cvt_bf16<<<(int)(N / 4 / 256), 256, 0, stream>>>(x, xbv, (int)(N / 4));
    cvt_bf16_w4<<<dim3((unsigned)(W / 4 / 256), 4), 256, 0, stream>>>(
        Wq, Wk, Wv, Wo, Wqb, Wkb, Wvb, Wob);

    gemm_qkv<<<dim3(DMODEL / 128, S_LEN / 128, 3), 256, 0, stream>>>(
        xbv, Wqb, bq, Wkb, bk, Wvb, bv, Qb, Kb, Vb);

    transpose_v<<<dim3(S_LEN / 64, DMODEL / 64), 256, 0, stream>>>(Vb, Vt);

    attn_kernel<<<1024, 256, 0, stream>>>(Qb, Kb, Vt, Ob);

    gemm_out<<<dim3(DMODEL / 128, S_LEN / 128), 256, 0, stream>>>(Ob, Wob, bo, out);
}